// Round 4
// baseline (1494.177 us; speedup 1.0000x reference)
//
#include <hip/hip_runtime.h>

#define NHID 48
#define BN_EPS 1e-5f
#define SLOPE 0.01f
#define DMAX 64

// ---------- bf16 helpers (fp32 compute, bf16 storage, RNE pack) ----------
__device__ __forceinline__ float bf_lo(unsigned u) { union { unsigned i; float f; } c; c.i = u << 16; return c.f; }
__device__ __forceinline__ float bf_hi(unsigned u) { union { unsigned i; float f; } c; c.i = u & 0xffff0000u; return c.f; }
__device__ __forceinline__ unsigned bf_rne(float x) { union { float f; unsigned i; } c; c.f = x; return (c.i + 0x7fffu + ((c.i >> 16) & 1u)) >> 16; }
__device__ __forceinline__ unsigned packbf(float lo, float hi) { return bf_rne(lo) | (bf_rne(hi) << 16); }

__device__ __forceinline__ void acc8(float (&a)[8], float w, const uint4& v) {
    a[0] = fmaf(w, bf_lo(v.x), a[0]); a[1] = fmaf(w, bf_hi(v.x), a[1]);
    a[2] = fmaf(w, bf_lo(v.y), a[2]); a[3] = fmaf(w, bf_hi(v.y), a[3]);
    a[4] = fmaf(w, bf_lo(v.z), a[4]); a[5] = fmaf(w, bf_hi(v.z), a[5]);
    a[6] = fmaf(w, bf_lo(v.w), a[6]); a[7] = fmaf(w, bf_hi(v.w), a[7]);
}

// ---------- setup: out-degree histogram + padded-CSR scatter in ONE edge pass ----------
__global__ void k_setup(const int* __restrict__ src, const int* __restrict__ dst,
                        float* __restrict__ degf, int* __restrict__ cur,
                        int* __restrict__ csrc, int nE) {
    int e = blockIdx.x * blockDim.x + threadIdx.x;
    if (e >= nE) return;
    int s = src[e], d = dst[e];
    atomicAdd(&degf[s], 1.0f);
    int r = atomicAdd(&cur[d], 1);
    if (r < DMAX) csrc[(size_t)d * DMAX + r] = s;
}

__global__ void k_dinv(float* __restrict__ deg, int nN) {
    int i = blockIdx.x * blockDim.x + threadIdx.x;
    if (i < nN) {
        float d = deg[i];
        deg[i] = (d > 0.f) ? rsqrtf(d) : 0.f;
    }
}

// ---------- degree counting-sort (bins 0..DMAX) ----------
__global__ void k_hist(const int* __restrict__ cur, int* __restrict__ hb, int nN) {
    __shared__ int lh[DMAX + 1];
    int t = threadIdx.x;
    if (t <= DMAX) lh[t] = 0;
    __syncthreads();
    for (int i = blockIdx.x * blockDim.x + t; i < nN; i += gridDim.x * blockDim.x) {
        int c = cur[i]; if (c > DMAX) c = DMAX;
        atomicAdd(&lh[c], 1);
    }
    __syncthreads();
    if (t <= DMAX) atomicAdd(&hb[t], lh[t]);
}

__global__ void k_scan65(const int* __restrict__ hb, int* __restrict__ hoff) {
    __shared__ int sh[128];
    int t = threadIdx.x;
    int v = (t <= DMAX) ? hb[t] : 0;
    sh[t] = v;
    __syncthreads();
    for (int o = 1; o < 128; o <<= 1) {
        int a = (t >= o) ? sh[t - o] : 0;
        __syncthreads();
        sh[t] += a;
        __syncthreads();
    }
    if (t <= DMAX) hoff[t] = sh[t] - v;  // exclusive
}

__global__ void k_order(const int* __restrict__ cur, int* __restrict__ hoff,
                        int* __restrict__ order, int nN) {
    int n = blockIdx.x * blockDim.x + threadIdx.x;
    if (n >= nN) return;
    int c = cur[n]; if (c > DMAX) c = DMAX;
    int r = atomicAdd(&hoff[c], 1);
    order[r] = n;
}

__global__ void k_cast(const float4* __restrict__ in, uint2* __restrict__ outv, int n4) {
    int i = blockIdx.x * blockDim.x + threadIdx.x;
    if (i < n4) {
        float4 v = in[i];
        outv[i] = make_uint2(packbf(v.x, v.y), packbf(v.z, v.w));
    }
}

// ---------- propagation (degree-sorted order, bf16 storage) ----------
template <int NV>
__global__ void k_prop(const uint4* __restrict__ Tin, const uint4* __restrict__ Tprev,
                       uint4* __restrict__ Tout, const int* __restrict__ cnt,
                       const int* __restrict__ csrc, const float* __restrict__ dinv,
                       const int* __restrict__ order, int nN, int mode) {
    int gid = blockIdx.x * 32 + threadIdx.y;
    if (gid >= nN) return;
    int n = order[gid];
    int f = threadIdx.x;
    int eb = n << 6;
    int c = cnt[n]; if (c > DMAX) c = DMAX;
    float a[8] = {0.f, 0.f, 0.f, 0.f, 0.f, 0.f, 0.f, 0.f};
    int j = 0;
    for (; j + 4 <= c; j += 4) {
        const int4 s4 = *(const int4*)(csrc + eb + j);
        float w0 = dinv[s4.x], w1 = dinv[s4.y], w2 = dinv[s4.z], w3 = dinv[s4.w];
        uint4 v0 = Tin[(size_t)s4.x * NV + f];
        uint4 v1 = Tin[(size_t)s4.y * NV + f];
        uint4 v2 = Tin[(size_t)s4.z * NV + f];
        uint4 v3 = Tin[(size_t)s4.w * NV + f];
        acc8(a, w0, v0); acc8(a, w1, v1); acc8(a, w2, v2); acc8(a, w3, v3);
    }
    for (; j < c; ++j) {
        int s = csrc[eb + j];
        acc8(a, dinv[s], Tin[(size_t)s * NV + f]);
    }
    float dn = -dinv[n];
    size_t o = (size_t)n * NV + f;
    uint4 r;
    if (mode) {
        uint4 p = Tprev[o];
        float t = 2.f * dn;
        r.x = packbf(fmaf(t, a[0], -bf_lo(p.x)), fmaf(t, a[1], -bf_hi(p.x)));
        r.y = packbf(fmaf(t, a[2], -bf_lo(p.y)), fmaf(t, a[3], -bf_hi(p.y)));
        r.z = packbf(fmaf(t, a[4], -bf_lo(p.z)), fmaf(t, a[5], -bf_hi(p.z)));
        r.w = packbf(fmaf(t, a[6], -bf_lo(p.w)), fmaf(t, a[7], -bf_hi(p.w)));
    } else {
        r.x = packbf(dn * a[0], dn * a[1]);
        r.y = packbf(dn * a[2], dn * a[3]);
        r.z = packbf(dn * a[4], dn * a[5]);
        r.w = packbf(dn * a[6], dn * a[7]);
    }
    Tout[o] = r;
}

// ---------- fused matmul over 5 Chebyshev terms ----------
// MODE 0: Hout(bf16) = bias + sum_t Tt @ W[t]; BN sums epilogue -> bns
// MODE 1: out(f32)  = (bias + sum_t Tt @ W[t]) @ Wf + bf   (final layer fused)
template <int NV, int MODE>
__global__ __launch_bounds__(384) void k_mm5(
    const uint4* __restrict__ T0, const uint4* __restrict__ T1, const uint4* __restrict__ T2,
    const uint4* __restrict__ T3, const uint4* __restrict__ T4,
    const float* __restrict__ Wb, const float* __restrict__ bias,
    unsigned short* __restrict__ Hout, float* __restrict__ bns,
    const float* __restrict__ Wf, const float* __restrict__ bfin,
    float* __restrict__ out, int nN) {
    __shared__ float sW[5 * NV * 8 * NHID];
    __shared__ float sE[8][NHID];
    __shared__ float sE2[8][NHID];
    __shared__ float sWf[NHID * 2 + 2];
    int j = threadIdx.x, y = threadIdx.y;
    int tid = y * NHID + j;
    const int tot = 5 * NV * 8 * NHID;
    for (int i = tid; i < tot; i += 384) sW[i] = Wb[i];
    if (MODE == 1) {
        if (tid < NHID * 2) sWf[tid] = Wf[tid];
        if (tid < 2) sWf[NHID * 2 + tid] = bfin[tid];
    }
    float bj = bias[j];
    float ss = 0.f, sq = 0.f;
    __syncthreads();
    const uint4* Ts[5] = {T0, T1, T2, T3, T4};
    const int ngroups = (nN + 7) / 8;
    for (int ng = blockIdx.x; ng < ngroups; ng += gridDim.x) {
        int n = ng * 8 + y;
        float acc = bj;
        if (n < nN) {
#pragma unroll
            for (int t = 0; t < 5; ++t) {
                const uint4* row = Ts[t] + (size_t)n * NV;
                const float* w = sW + t * NV * 8 * NHID + j;
#pragma unroll
                for (int f4 = 0; f4 < NV; ++f4) {
                    uint4 v = row[f4];
                    const float* wb = w + f4 * 8 * NHID;
                    acc = fmaf(bf_lo(v.x), wb[0 * NHID], acc);
                    acc = fmaf(bf_hi(v.x), wb[1 * NHID], acc);
                    acc = fmaf(bf_lo(v.y), wb[2 * NHID], acc);
                    acc = fmaf(bf_hi(v.y), wb[3 * NHID], acc);
                    acc = fmaf(bf_lo(v.z), wb[4 * NHID], acc);
                    acc = fmaf(bf_hi(v.z), wb[5 * NHID], acc);
                    acc = fmaf(bf_lo(v.w), wb[6 * NHID], acc);
                    acc = fmaf(bf_hi(v.w), wb[7 * NHID], acc);
                }
            }
        }
        if (MODE == 0) {
            if (n < nN) {
                Hout[(size_t)n * NHID + j] = (unsigned short)bf_rne(acc);
                ss += acc; sq += acc * acc;
            }
        } else {
            __syncthreads();
            sE[y][j] = acc;
            __syncthreads();
            if (j < 2 && n < nN) {
                float a = sWf[NHID * 2 + j];
#pragma unroll
                for (int f = 0; f < NHID; ++f) a = fmaf(sE[y][f], sWf[f * 2 + j], a);
                out[(size_t)n * 2 + j] = a;
            }
        }
    }
    if (MODE == 0) {
        sE[y][j] = ss; sE2[y][j] = sq;
        __syncthreads();
        if (y == 0) {
#pragma unroll
            for (int yy = 1; yy < 8; ++yy) { ss += sE[yy][j]; sq += sE2[yy][j]; }
            atomicAdd(&bns[j], ss);
            atomicAdd(&bns[NHID + j], sq);
        }
    }
}

// ---------- batchnorm apply + LeakyReLU ----------
__global__ void k_bn_apply(unsigned short* __restrict__ X, const float* __restrict__ sums,
                           const float* __restrict__ g, const float* __restrict__ b,
                           int nN) {
    int n = blockIdx.x * 8 + threadIdx.y;
    if (n >= nN) return;
    int col = threadIdx.x;
    float inv = 1.f / (float)nN;
    float mu = sums[col] * inv;
    float var = sums[NHID + col] * inv - mu * mu;
    size_t o = (size_t)n * NHID + col;
    float y = (bf_lo(X[o]) - mu) * rsqrtf(var + BN_EPS) * g[col] + b[col];
    y = (y >= 0.f) ? y : SLOPE * y;
    X[o] = (unsigned short)bf_rne(y);
}

extern "C" void kernel_launch(void* const* d_in, const int* in_sizes, int n_in,
                              void* d_out, int out_size, void* d_ws, size_t ws_size,
                              hipStream_t stream) {
    const float* x   = (const float*)d_in[0];
    const int*   ei  = (const int*)d_in[1];
    const float* W1  = (const float*)d_in[2];
    const float* b1  = (const float*)d_in[3];
    const float* W2  = (const float*)d_in[4];
    const float* b2  = (const float*)d_in[5];
    const float* W3  = (const float*)d_in[6];
    const float* b3  = (const float*)d_in[7];
    const float* g1  = (const float*)d_in[8];
    const float* bt1 = (const float*)d_in[9];
    const float* g2  = (const float*)d_in[10];
    const float* bt2 = (const float*)d_in[11];
    const float* Wf  = (const float*)d_in[12];
    const float* bf  = (const float*)d_in[13];
    float* out = (float*)d_out;

    const int nN = in_sizes[0] / 64;
    const int nE = in_sizes[1] / 2;
    const int* src = ei;
    const int* dst = ei + nE;

    size_t off = 0;
    auto carve = [&](size_t bytes) -> void* {
        void* p = (char*)d_ws + off;
        off += (bytes + 255) & ~(size_t)255;
        return p;
    };
    float*          dinv  = (float*)carve((size_t)nN * 4);
    int*            cur   = (int*)carve((size_t)nN * 4);
    int*            hb    = (int*)carve((DMAX + 1) * 4);
    int*            hoff  = (int*)carve((DMAX + 1) * 4);
    int*            order = (int*)carve((size_t)nN * 4);
    int*            csrc  = (int*)carve((size_t)nN * DMAX * 4);
    uint4*          X0    = (uint4*)carve((size_t)nN * 8 * 16);
    uint4*          T1    = (uint4*)carve((size_t)nN * 8 * 16);
    uint4*          T2    = (uint4*)carve((size_t)nN * 8 * 16);
    uint4*          T3    = (uint4*)carve((size_t)nN * 8 * 16);
    uint4*          T4    = (uint4*)carve((size_t)nN * 8 * 16);
    unsigned short* H1    = (unsigned short*)carve((size_t)nN * NHID * 2);
    unsigned short* H2    = (unsigned short*)carve((size_t)nN * NHID * 2);
    float*          bns   = (float*)carve(2 * NHID * 4);

    hipMemsetAsync(dinv, 0, (size_t)nN * 4, stream);
    hipMemsetAsync(cur, 0, (size_t)nN * 4, stream);
    hipMemsetAsync(hb, 0, (DMAX + 1) * 4, stream);

    const int gE = (nE + 255) / 256;
    k_setup<<<gE, 256, 0, stream>>>(src, dst, dinv, cur, csrc, nE);
    k_dinv<<<(nN + 255) / 256, 256, 0, stream>>>(dinv, nN);
    k_hist<<<256, 256, 0, stream>>>(cur, hb, nN);
    k_scan65<<<1, 128, 0, stream>>>(hb, hoff);
    k_order<<<(nN + 255) / 256, 256, 0, stream>>>(cur, hoff, order, nN);
    k_cast<<<(nN * 16 + 255) / 256, 256, 0, stream>>>((const float4*)x, (uint2*)X0, nN * 16);

    const int gP = (nN + 31) / 32;
    const int gM = 1024;
    dim3 blkM(NHID, 8);

    auto prop = [&](const uint4* Tin, const uint4* Tprev, uint4* Tout, int NVw, int mode) {
        if (NVw == 8) {
            dim3 blk(8, 32);
            k_prop<8><<<gP, blk, 0, stream>>>(Tin, Tprev, Tout, cur, csrc, dinv, order, nN, mode);
        } else {
            dim3 blk(6, 32);
            k_prop<6><<<gP, blk, 0, stream>>>(Tin, Tprev, Tout, cur, csrc, dinv, order, nN, mode);
        }
    };

    // ---- layer 1 (Win=64) ----
    prop(X0, nullptr, T1, 8, 0);
    prop(T1, X0, T2, 8, 1);
    prop(T2, T1, T3, 8, 1);
    prop(T3, T2, T4, 8, 1);
    hipMemsetAsync(bns, 0, 2 * NHID * 4, stream);
    k_mm5<8, 0><<<gM, blkM, 0, stream>>>(X0, T1, T2, T3, T4, W1, b1, H1, bns, Wf, bf, out, nN);
    k_bn_apply<<<(nN + 7) / 8, dim3(NHID, 8), 0, stream>>>(H1, bns, g1, bt1, nN);

    // ---- layer 2 (Win=48) ----
    prop((uint4*)H1, nullptr, T1, 6, 0);
    prop(T1, (uint4*)H1, T2, 6, 1);
    prop(T2, T1, T3, 6, 1);
    prop(T3, T2, T4, 6, 1);
    hipMemsetAsync(bns, 0, 2 * NHID * 4, stream);
    k_mm5<6, 0><<<gM, blkM, 0, stream>>>((uint4*)H1, T1, T2, T3, T4, W2, b2, H2, bns, Wf, bf, out, nN);
    k_bn_apply<<<(nN + 7) / 8, dim3(NHID, 8), 0, stream>>>(H2, bns, g2, bt2, nN);

    // ---- layer 3 (Win=48) + fused final linear ----
    prop((uint4*)H2, nullptr, T1, 6, 0);
    prop(T1, (uint4*)H2, T2, 6, 1);
    prop(T2, T1, T3, 6, 1);
    prop(T3, T2, T4, 6, 1);
    k_mm5<6, 1><<<gM, blkM, 0, stream>>>((uint4*)H2, T1, T2, T3, T4, W3, b3, nullptr, nullptr, Wf, bf, out, nN);
}

// Round 5
// 1257.848 us; speedup vs baseline: 1.1879x; 1.1879x over previous
//
#include <hip/hip_runtime.h>

#define NHID 48
#define BN_EPS 1e-5f
#define SLOPE 0.01f
#define DMAX 64

// ---------- bf16 helpers (fp32 compute, bf16 storage, RNE pack) ----------
__device__ __forceinline__ float bf_lo(unsigned u) { union { unsigned i; float f; } c; c.i = u << 16; return c.f; }
__device__ __forceinline__ float bf_hi(unsigned u) { union { unsigned i; float f; } c; c.i = u & 0xffff0000u; return c.f; }
__device__ __forceinline__ unsigned bf_rne(float x) { union { float f; unsigned i; } c; c.f = x; return (c.i + 0x7fffu + ((c.i >> 16) & 1u)) >> 16; }
__device__ __forceinline__ unsigned packbf(float lo, float hi) { return bf_rne(lo) | (bf_rne(hi) << 16); }

__device__ __forceinline__ void acc8(float (&a)[8], float w, const uint4& v) {
    a[0] = fmaf(w, bf_lo(v.x), a[0]); a[1] = fmaf(w, bf_hi(v.x), a[1]);
    a[2] = fmaf(w, bf_lo(v.y), a[2]); a[3] = fmaf(w, bf_hi(v.y), a[3]);
    a[4] = fmaf(w, bf_lo(v.z), a[4]); a[5] = fmaf(w, bf_hi(v.z), a[5]);
    a[6] = fmaf(w, bf_lo(v.w), a[6]); a[7] = fmaf(w, bf_hi(v.w), a[7]);
}

// ---------- setup: out-degree histogram + padded-CSR scatter in ONE edge pass ----------
__global__ void k_setup(const int* __restrict__ src, const int* __restrict__ dst,
                        float* __restrict__ degf, int* __restrict__ cur,
                        int* __restrict__ csrc, int nE) {
    int e = blockIdx.x * blockDim.x + threadIdx.x;
    if (e >= nE) return;
    int s = src[e], d = dst[e];
    atomicAdd(&degf[s], 1.0f);
    int r = atomicAdd(&cur[d], 1);
    if (r < DMAX) csrc[(size_t)d * DMAX + r] = s;
}

__global__ void k_dinv(float* __restrict__ deg, int nN) {
    int i = blockIdx.x * blockDim.x + threadIdx.x;
    if (i < nN) {
        float d = deg[i];
        deg[i] = (d > 0.f) ? rsqrtf(d) : 0.f;
    }
}

__global__ void k_cast(const float4* __restrict__ in, uint2* __restrict__ outv, int n4) {
    int i = blockIdx.x * blockDim.x + threadIdx.x;
    if (i < n4) {
        float4 v = in[i];
        outv[i] = make_uint2(packbf(v.x, v.y), packbf(v.z, v.w));
    }
}

// ---------- propagation: ONE WAVE PER NODE ----------
// lane = y*8 + x : y = edge slot (0..7), x = uint4 feature chunk (0..NV-1)
// 16 edges in flight per iteration (2 slots unrolled); iterations = ceil(c/16)
// reduce over y via shfl_xor(8,16,32); lanes y==0 write the node row.
template <int NV>
__global__ void k_prop(const uint4* __restrict__ Tin, const uint4* __restrict__ Tprev,
                       uint4* __restrict__ Tout, const int* __restrict__ cnt,
                       const int* __restrict__ csrc, const float* __restrict__ dinv,
                       int nN, int mode) {
    int n = blockIdx.x * 4 + threadIdx.y;
    if (n >= nN) return;
    int lane = threadIdx.x;
    int x = lane & 7;
    int y = lane >> 3;
    int eb = n << 6;
    int c = cnt[n]; if (c > DMAX) c = DMAX;
    float a[8] = {0.f, 0.f, 0.f, 0.f, 0.f, 0.f, 0.f, 0.f};
    for (int it = 0; it < c; it += 16) {
        int j0 = it + y, j1 = it + 8 + y;
        int s0 = (j0 < c) ? csrc[eb + j0] : 0;
        int s1 = (j1 < c) ? csrc[eb + j1] : 0;
        float w0 = (j0 < c) ? dinv[s0] : 0.f;
        float w1 = (j1 < c) ? dinv[s1] : 0.f;
        if (x < NV) {
            uint4 q0 = Tin[(size_t)s0 * NV + x];
            uint4 q1 = Tin[(size_t)s1 * NV + x];
            acc8(a, w0, q0);
            acc8(a, w1, q1);
        }
    }
#pragma unroll
    for (int k = 0; k < 8; ++k) {
        float v = a[k];
        v += __shfl_xor(v, 8);
        v += __shfl_xor(v, 16);
        v += __shfl_xor(v, 32);
        a[k] = v;
    }
    if (y == 0 && x < NV) {
        float dn = -dinv[n];
        size_t o = (size_t)n * NV + x;
        uint4 r;
        if (mode) {
            uint4 p = Tprev[o];
            float t = 2.f * dn;
            r.x = packbf(fmaf(t, a[0], -bf_lo(p.x)), fmaf(t, a[1], -bf_hi(p.x)));
            r.y = packbf(fmaf(t, a[2], -bf_lo(p.y)), fmaf(t, a[3], -bf_hi(p.y)));
            r.z = packbf(fmaf(t, a[4], -bf_lo(p.z)), fmaf(t, a[5], -bf_hi(p.z)));
            r.w = packbf(fmaf(t, a[6], -bf_lo(p.w)), fmaf(t, a[7], -bf_hi(p.w)));
        } else {
            r.x = packbf(dn * a[0], dn * a[1]);
            r.y = packbf(dn * a[2], dn * a[3]);
            r.z = packbf(dn * a[4], dn * a[5]);
            r.w = packbf(dn * a[6], dn * a[7]);
        }
        Tout[o] = r;
    }
}

// ---------- fused matmul over 5 Chebyshev terms ----------
// MODE 0: Hout(bf16) = bias + sum_t Tt @ W[t]; BN sums epilogue -> bns
// MODE 1: out(f32)  = (bias + sum_t Tt @ W[t]) @ Wf + bf   (final layer fused)
template <int NV, int MODE>
__global__ __launch_bounds__(384) void k_mm5(
    const uint4* __restrict__ T0, const uint4* __restrict__ T1, const uint4* __restrict__ T2,
    const uint4* __restrict__ T3, const uint4* __restrict__ T4,
    const float* __restrict__ Wb, const float* __restrict__ bias,
    unsigned short* __restrict__ Hout, float* __restrict__ bns,
    const float* __restrict__ Wf, const float* __restrict__ bfin,
    float* __restrict__ out, int nN) {
    __shared__ float sW[5 * NV * 8 * NHID];
    __shared__ float sE[8][NHID];
    __shared__ float sE2[8][NHID];
    __shared__ float sWf[NHID * 2 + 2];
    int j = threadIdx.x, y = threadIdx.y;
    int tid = y * NHID + j;
    const int tot = 5 * NV * 8 * NHID;
    for (int i = tid; i < tot; i += 384) sW[i] = Wb[i];
    if (MODE == 1) {
        if (tid < NHID * 2) sWf[tid] = Wf[tid];
        if (tid < 2) sWf[NHID * 2 + tid] = bfin[tid];
    }
    float bj = bias[j];
    float ss = 0.f, sq = 0.f;
    __syncthreads();
    const uint4* Ts[5] = {T0, T1, T2, T3, T4};
    const int ngroups = (nN + 7) / 8;
    for (int ng = blockIdx.x; ng < ngroups; ng += gridDim.x) {
        int n = ng * 8 + y;
        float acc = bj;
        if (n < nN) {
#pragma unroll
            for (int t = 0; t < 5; ++t) {
                const uint4* row = Ts[t] + (size_t)n * NV;
                const float* w = sW + t * NV * 8 * NHID + j;
#pragma unroll
                for (int f4 = 0; f4 < NV; ++f4) {
                    uint4 v = row[f4];
                    const float* wb = w + f4 * 8 * NHID;
                    acc = fmaf(bf_lo(v.x), wb[0 * NHID], acc);
                    acc = fmaf(bf_hi(v.x), wb[1 * NHID], acc);
                    acc = fmaf(bf_lo(v.y), wb[2 * NHID], acc);
                    acc = fmaf(bf_hi(v.y), wb[3 * NHID], acc);
                    acc = fmaf(bf_lo(v.z), wb[4 * NHID], acc);
                    acc = fmaf(bf_hi(v.z), wb[5 * NHID], acc);
                    acc = fmaf(bf_lo(v.w), wb[6 * NHID], acc);
                    acc = fmaf(bf_hi(v.w), wb[7 * NHID], acc);
                }
            }
        }
        if (MODE == 0) {
            if (n < nN) {
                Hout[(size_t)n * NHID + j] = (unsigned short)bf_rne(acc);
                ss += acc; sq += acc * acc;
            }
        } else {
            __syncthreads();
            sE[y][j] = acc;
            __syncthreads();
            if (j < 2 && n < nN) {
                float a = sWf[NHID * 2 + j];
#pragma unroll
                for (int f = 0; f < NHID; ++f) a = fmaf(sE[y][f], sWf[f * 2 + j], a);
                out[(size_t)n * 2 + j] = a;
            }
        }
    }
    if (MODE == 0) {
        sE[y][j] = ss; sE2[y][j] = sq;
        __syncthreads();
        if (y == 0) {
#pragma unroll
            for (int yy = 1; yy < 8; ++yy) { ss += sE[yy][j]; sq += sE2[yy][j]; }
            atomicAdd(&bns[j], ss);
            atomicAdd(&bns[NHID + j], sq);
        }
    }
}

// ---------- batchnorm apply + LeakyReLU ----------
__global__ void k_bn_apply(unsigned short* __restrict__ X, const float* __restrict__ sums,
                           const float* __restrict__ g, const float* __restrict__ b,
                           int nN) {
    int n = blockIdx.x * 8 + threadIdx.y;
    if (n >= nN) return;
    int col = threadIdx.x;
    float inv = 1.f / (float)nN;
    float mu = sums[col] * inv;
    float var = sums[NHID + col] * inv - mu * mu;
    size_t o = (size_t)n * NHID + col;
    float y = (bf_lo(X[o]) - mu) * rsqrtf(var + BN_EPS) * g[col] + b[col];
    y = (y >= 0.f) ? y : SLOPE * y;
    X[o] = (unsigned short)bf_rne(y);
}

extern "C" void kernel_launch(void* const* d_in, const int* in_sizes, int n_in,
                              void* d_out, int out_size, void* d_ws, size_t ws_size,
                              hipStream_t stream) {
    const float* x   = (const float*)d_in[0];
    const int*   ei  = (const int*)d_in[1];
    const float* W1  = (const float*)d_in[2];
    const float* b1  = (const float*)d_in[3];
    const float* W2  = (const float*)d_in[4];
    const float* b2  = (const float*)d_in[5];
    const float* W3  = (const float*)d_in[6];
    const float* b3  = (const float*)d_in[7];
    const float* g1  = (const float*)d_in[8];
    const float* bt1 = (const float*)d_in[9];
    const float* g2  = (const float*)d_in[10];
    const float* bt2 = (const float*)d_in[11];
    const float* Wf  = (const float*)d_in[12];
    const float* bf  = (const float*)d_in[13];
    float* out = (float*)d_out;

    const int nN = in_sizes[0] / 64;
    const int nE = in_sizes[1] / 2;
    const int* src = ei;
    const int* dst = ei + nE;

    size_t off = 0;
    auto carve = [&](size_t bytes) -> void* {
        void* p = (char*)d_ws + off;
        off += (bytes + 255) & ~(size_t)255;
        return p;
    };
    float*          dinv = (float*)carve((size_t)nN * 4);
    int*            cur  = (int*)carve((size_t)nN * 4);
    int*            csrc = (int*)carve((size_t)nN * DMAX * 4);
    uint4*          X0   = (uint4*)carve((size_t)nN * 8 * 16);
    uint4*          T1   = (uint4*)carve((size_t)nN * 8 * 16);
    uint4*          T2   = (uint4*)carve((size_t)nN * 8 * 16);
    uint4*          T3   = (uint4*)carve((size_t)nN * 8 * 16);
    uint4*          T4   = (uint4*)carve((size_t)nN * 8 * 16);
    unsigned short* H1   = (unsigned short*)carve((size_t)nN * NHID * 2);
    unsigned short* H2   = (unsigned short*)carve((size_t)nN * NHID * 2);
    float*          bns  = (float*)carve(2 * NHID * 4);

    hipMemsetAsync(dinv, 0, (size_t)nN * 4, stream);
    hipMemsetAsync(cur, 0, (size_t)nN * 4, stream);

    const int gE = (nE + 255) / 256;
    k_setup<<<gE, 256, 0, stream>>>(src, dst, dinv, cur, csrc, nE);
    k_dinv<<<(nN + 255) / 256, 256, 0, stream>>>(dinv, nN);
    k_cast<<<(nN * 16 + 255) / 256, 256, 0, stream>>>((const float4*)x, (uint2*)X0, nN * 16);

    const int gP = (nN + 3) / 4;
    const dim3 blkP(64, 4);
    const int gM = 512;
    dim3 blkM(NHID, 8);

    auto prop = [&](const uint4* Tin, const uint4* Tprev, uint4* Tout, int NVw, int mode) {
        if (NVw == 8)
            k_prop<8><<<gP, blkP, 0, stream>>>(Tin, Tprev, Tout, cur, csrc, dinv, nN, mode);
        else
            k_prop<6><<<gP, blkP, 0, stream>>>(Tin, Tprev, Tout, cur, csrc, dinv, nN, mode);
    };

    // ---- layer 1 (Win=64) ----
    prop(X0, nullptr, T1, 8, 0);
    prop(T1, X0, T2, 8, 1);
    prop(T2, T1, T3, 8, 1);
    prop(T3, T2, T4, 8, 1);
    hipMemsetAsync(bns, 0, 2 * NHID * 4, stream);
    k_mm5<8, 0><<<gM, blkM, 0, stream>>>(X0, T1, T2, T3, T4, W1, b1, H1, bns, Wf, bf, out, nN);
    k_bn_apply<<<(nN + 7) / 8, dim3(NHID, 8), 0, stream>>>(H1, bns, g1, bt1, nN);

    // ---- layer 2 (Win=48) ----
    prop((uint4*)H1, nullptr, T1, 6, 0);
    prop(T1, (uint4*)H1, T2, 6, 1);
    prop(T2, T1, T3, 6, 1);
    prop(T3, T2, T4, 6, 1);
    hipMemsetAsync(bns, 0, 2 * NHID * 4, stream);
    k_mm5<6, 0><<<gM, blkM, 0, stream>>>((uint4*)H1, T1, T2, T3, T4, W2, b2, H2, bns, Wf, bf, out, nN);
    k_bn_apply<<<(nN + 7) / 8, dim3(NHID, 8), 0, stream>>>(H2, bns, g2, bt2, nN);

    // ---- layer 3 (Win=48) + fused final linear ----
    prop((uint4*)H2, nullptr, T1, 6, 0);
    prop(T1, (uint4*)H2, T2, 6, 1);
    prop(T2, T1, T3, 6, 1);
    prop(T3, T2, T4, 6, 1);
    k_mm5<6, 1><<<gM, blkM, 0, stream>>>((uint4*)H2, T1, T2, T3, T4, W3, b3, nullptr, nullptr, Wf, bf, out, nN);
}

// Round 6
// 849.762 us; speedup vs baseline: 1.7583x; 1.4802x over previous
//
#include <hip/hip_runtime.h>

#define NHID 48
#define BN_EPS 1e-5f
#define SLOPE 0.01f
#define DMAX 64

typedef short short8 __attribute__((ext_vector_type(8)));
typedef float f32x4 __attribute__((ext_vector_type(4)));

// ---------- bf16 helpers (fp32 compute, bf16 storage, RNE pack) ----------
__device__ __forceinline__ float bf_lo(unsigned u) { union { unsigned i; float f; } c; c.i = u << 16; return c.f; }
__device__ __forceinline__ float bf_hi(unsigned u) { union { unsigned i; float f; } c; c.i = u & 0xffff0000u; return c.f; }
__device__ __forceinline__ unsigned bf_rne(float x) { union { float f; unsigned i; } c; c.f = x; return (c.i + 0x7fffu + ((c.i >> 16) & 1u)) >> 16; }
__device__ __forceinline__ unsigned packbf(float lo, float hi) { return bf_rne(lo) | (bf_rne(hi) << 16); }

__device__ __forceinline__ void acc8(float (&a)[8], float w, const uint4& v) {
    a[0] = fmaf(w, bf_lo(v.x), a[0]); a[1] = fmaf(w, bf_hi(v.x), a[1]);
    a[2] = fmaf(w, bf_lo(v.y), a[2]); a[3] = fmaf(w, bf_hi(v.y), a[3]);
    a[4] = fmaf(w, bf_lo(v.z), a[4]); a[5] = fmaf(w, bf_hi(v.z), a[5]);
    a[6] = fmaf(w, bf_lo(v.w), a[6]); a[7] = fmaf(w, bf_hi(v.w), a[7]);
}

// ---------- setup: out-degree histogram + padded-CSR scatter in ONE edge pass ----------
__global__ void k_setup(const int* __restrict__ src, const int* __restrict__ dst,
                        float* __restrict__ degf, int* __restrict__ cur,
                        int* __restrict__ csrc, int nE) {
    int e = blockIdx.x * blockDim.x + threadIdx.x;
    if (e >= nE) return;
    int s = src[e], d = dst[e];
    atomicAdd(&degf[s], 1.0f);
    int r = atomicAdd(&cur[d], 1);
    if (r < DMAX) csrc[(size_t)d * DMAX + r] = s;
}

__global__ void k_dinv(float* __restrict__ deg, int nN) {
    int i = blockIdx.x * blockDim.x + threadIdx.x;
    if (i < nN) {
        float d = deg[i];
        deg[i] = (d > 0.f) ? rsqrtf(d) : 0.f;
    }
}

__global__ void k_cast(const float4* __restrict__ in, uint2* __restrict__ outv, int n4) {
    int i = blockIdx.x * blockDim.x + threadIdx.x;
    if (i < n4) {
        float4 v = in[i];
        outv[i] = make_uint2(packbf(v.x, v.y), packbf(v.z, v.w));
    }
}

// ---------- propagation: one wave per node (unchanged from R5) ----------
template <int NV>
__global__ void k_prop(const uint4* __restrict__ Tin, const uint4* __restrict__ Tprev,
                       uint4* __restrict__ Tout, const int* __restrict__ cnt,
                       const int* __restrict__ csrc, const float* __restrict__ dinv,
                       int nN, int mode) {
    int n = blockIdx.x * 4 + threadIdx.y;
    if (n >= nN) return;
    int lane = threadIdx.x;
    int x = lane & 7;
    int y = lane >> 3;
    int eb = n << 6;
    int c = cnt[n]; if (c > DMAX) c = DMAX;
    float a[8] = {0.f, 0.f, 0.f, 0.f, 0.f, 0.f, 0.f, 0.f};
    for (int it = 0; it < c; it += 16) {
        int j0 = it + y, j1 = it + 8 + y;
        int s0 = (j0 < c) ? csrc[eb + j0] : 0;
        int s1 = (j1 < c) ? csrc[eb + j1] : 0;
        float w0 = (j0 < c) ? dinv[s0] : 0.f;
        float w1 = (j1 < c) ? dinv[s1] : 0.f;
        if (x < NV) {
            uint4 q0 = Tin[(size_t)s0 * NV + x];
            uint4 q1 = Tin[(size_t)s1 * NV + x];
            acc8(a, w0, q0);
            acc8(a, w1, q1);
        }
    }
#pragma unroll
    for (int k = 0; k < 8; ++k) {
        float v = a[k];
        v += __shfl_xor(v, 8);
        v += __shfl_xor(v, 16);
        v += __shfl_xor(v, 32);
        a[k] = v;
    }
    if (y == 0 && x < NV) {
        float dn = -dinv[n];
        size_t o = (size_t)n * NV + x;
        uint4 r;
        if (mode) {
            uint4 p = Tprev[o];
            float t = 2.f * dn;
            r.x = packbf(fmaf(t, a[0], -bf_lo(p.x)), fmaf(t, a[1], -bf_hi(p.x)));
            r.y = packbf(fmaf(t, a[2], -bf_lo(p.y)), fmaf(t, a[3], -bf_hi(p.y)));
            r.z = packbf(fmaf(t, a[4], -bf_lo(p.z)), fmaf(t, a[5], -bf_hi(p.z)));
            r.w = packbf(fmaf(t, a[6], -bf_lo(p.w)), fmaf(t, a[7], -bf_hi(p.w)));
        } else {
            r.x = packbf(dn * a[0], dn * a[1]);
            r.y = packbf(dn * a[2], dn * a[3]);
            r.z = packbf(dn * a[4], dn * a[5]);
            r.w = packbf(dn * a[6], dn * a[7]);
        }
        Tout[o] = r;
    }
}

// ---------- MFMA matmul over 5 Chebyshev terms ----------
// Tslab: [5][nN][WIN] bf16 contiguous; W: [K=5*WIN][48] fp32 (k = t*WIN+f matches)
// MODE 0: Hout(bf16) = bias + slab@W; BN sums epilogue -> bns
// MODE 1: out(f32)   = (bias + slab@W) @ Wf + bf
template <int WIN, int MODE>
__global__ __launch_bounds__(256) void k_mmf(
    const unsigned short* __restrict__ Tslab, const float* __restrict__ Wb,
    const float* __restrict__ bias, unsigned short* __restrict__ Hout,
    float* __restrict__ bns, const float* __restrict__ Wf,
    const float* __restrict__ bfin, float* __restrict__ out, int nN) {
    constexpr int K = 5 * WIN;
    constexpr int NC = (K + 31) / 32;   // 10 (WIN=64) or 8 (WIN=48, last half-padded)
    const int lane = threadIdx.x & 63;
    const int wid = threadIdx.x >> 6;
    const int col = lane & 15;
    const int sub = lane >> 4;
    const size_t termStride = (size_t)nN * WIN;

    // B fragments in registers: lane holds B[k=(sub*8+r)+32c][j=ct*16+col]
    short8 bfrag[3][NC];
#pragma unroll
    for (int ct = 0; ct < 3; ++ct) {
        int j = ct * 16 + col;
#pragma unroll
        for (int c = 0; c < NC; ++c) {
            short8 b;
#pragma unroll
            for (int r = 0; r < 8; ++r) {
                int k = c * 32 + sub * 8 + r;
                float w = (k < K) ? Wb[(size_t)k * 48 + j] : 0.f;
                b[r] = (short)bf_rne(w);
            }
            bfrag[ct][c] = b;
        }
    }
    float bj0 = bias[col], bj1 = bias[16 + col], bj2 = bias[32 + col];
    float wf00 = 0.f, wf01 = 0.f, wf02 = 0.f, wf10 = 0.f, wf11 = 0.f, wf12 = 0.f;
    float bf0 = 0.f, bf1 = 0.f;
    if (MODE == 1) {
        wf00 = Wf[(col) * 2 + 0];      wf10 = Wf[(col) * 2 + 1];
        wf01 = Wf[(16 + col) * 2 + 0]; wf11 = Wf[(16 + col) * 2 + 1];
        wf02 = Wf[(32 + col) * 2 + 0]; wf12 = Wf[(32 + col) * 2 + 1];
        bf0 = bfin[0]; bf1 = bfin[1];
    }
    float s0 = 0.f, s1 = 0.f, s2 = 0.f, q0 = 0.f, q1 = 0.f, q2 = 0.f;

    const int ntiles = (nN + 15) >> 4;
    for (int tile = blockIdx.x * 4 + wid; tile < ntiles; tile += gridDim.x * 4) {
        int n0 = tile << 4;
        int arow = n0 + col;            // A row this lane supplies
        bool rowok = arow < nN;
        f32x4 acc0 = {0.f, 0.f, 0.f, 0.f};
        f32x4 acc1 = {0.f, 0.f, 0.f, 0.f};
        f32x4 acc2 = {0.f, 0.f, 0.f, 0.f};
#pragma unroll
        for (int c = 0; c < NC; ++c) {
            int k = c * 32 + sub * 8;
            short8 a = {};
            if (rowok && k < K) {
                int t = k / WIN, f = k % WIN;
                a = *(const short8*)(Tslab + (size_t)t * termStride + (size_t)arow * WIN + f);
            }
            acc0 = __builtin_amdgcn_mfma_f32_16x16x32_bf16(a, bfrag[0][c], acc0, 0, 0, 0);
            acc1 = __builtin_amdgcn_mfma_f32_16x16x32_bf16(a, bfrag[1][c], acc1, 0, 0, 0);
            acc2 = __builtin_amdgcn_mfma_f32_16x16x32_bf16(a, bfrag[2][c], acc2, 0, 0, 0);
        }
        int nb = n0 + sub * 4;          // D rows: (lane>>4)*4 + reg
        if (MODE == 0) {
#pragma unroll
            for (int r = 0; r < 4; ++r) {
                int n = nb + r;
                if (n < nN) {
                    float v0 = acc0[r] + bj0;
                    float v1 = acc1[r] + bj1;
                    float v2 = acc2[r] + bj2;
                    size_t ro = (size_t)n * NHID;
                    Hout[ro + col]      = (unsigned short)bf_rne(v0);
                    Hout[ro + 16 + col] = (unsigned short)bf_rne(v1);
                    Hout[ro + 32 + col] = (unsigned short)bf_rne(v2);
                    s0 += v0; q0 += v0 * v0;
                    s1 += v1; q1 += v1 * v1;
                    s2 += v2; q2 += v2 * v2;
                }
            }
        } else {
#pragma unroll
            for (int r = 0; r < 4; ++r) {
                float p0 = fmaf(acc0[r] + bj0, wf00, fmaf(acc1[r] + bj1, wf01, (acc2[r] + bj2) * wf02));
                float p1 = fmaf(acc0[r] + bj0, wf10, fmaf(acc1[r] + bj1, wf11, (acc2[r] + bj2) * wf12));
                p0 += __shfl_xor(p0, 1); p0 += __shfl_xor(p0, 2);
                p0 += __shfl_xor(p0, 4); p0 += __shfl_xor(p0, 8);
                p1 += __shfl_xor(p1, 1); p1 += __shfl_xor(p1, 2);
                p1 += __shfl_xor(p1, 4); p1 += __shfl_xor(p1, 8);
                int n = nb + r;
                if (col == 0 && n < nN) {
                    out[(size_t)n * 2 + 0] = p0 + bf0;
                    out[(size_t)n * 2 + 1] = p1 + bf1;
                }
            }
        }
    }
    if (MODE == 0) {
        // fold rows (sub groups) -> per-col sums, then block-reduce -> 96 atomics
        s0 += __shfl_xor(s0, 16); s0 += __shfl_xor(s0, 32);
        s1 += __shfl_xor(s1, 16); s1 += __shfl_xor(s1, 32);
        s2 += __shfl_xor(s2, 16); s2 += __shfl_xor(s2, 32);
        q0 += __shfl_xor(q0, 16); q0 += __shfl_xor(q0, 32);
        q1 += __shfl_xor(q1, 16); q1 += __shfl_xor(q1, 32);
        q2 += __shfl_xor(q2, 16); q2 += __shfl_xor(q2, 32);
        __shared__ float red[4][96];
        if (lane < 16) {
            red[wid][col]      = s0; red[wid][16 + col] = s1; red[wid][32 + col] = s2;
            red[wid][48 + col] = q0; red[wid][64 + col] = q1; red[wid][80 + col] = q2;
        }
        __syncthreads();
        int t = threadIdx.x;
        if (t < 96) atomicAdd(&bns[t], red[0][t] + red[1][t] + red[2][t] + red[3][t]);
    }
}

// ---------- batchnorm apply + LeakyReLU: Hin(bf16) -> Tout0(bf16, next layer term0) ----------
__global__ void k_bn_apply(const unsigned short* __restrict__ Hin, unsigned short* __restrict__ T0,
                           const float* __restrict__ sums, const float* __restrict__ g,
                           const float* __restrict__ b, int nN) {
    int n = blockIdx.x * 8 + threadIdx.y;
    if (n >= nN) return;
    int col = threadIdx.x;
    float inv = 1.f / (float)nN;
    float mu = sums[col] * inv;
    float var = sums[NHID + col] * inv - mu * mu;
    size_t o = (size_t)n * NHID + col;
    float y = (bf_lo(Hin[o]) - mu) * rsqrtf(var + BN_EPS) * g[col] + b[col];
    y = (y >= 0.f) ? y : SLOPE * y;
    T0[o] = (unsigned short)bf_rne(y);
}

extern "C" void kernel_launch(void* const* d_in, const int* in_sizes, int n_in,
                              void* d_out, int out_size, void* d_ws, size_t ws_size,
                              hipStream_t stream) {
    const float* x   = (const float*)d_in[0];
    const int*   ei  = (const int*)d_in[1];
    const float* W1  = (const float*)d_in[2];
    const float* b1  = (const float*)d_in[3];
    const float* W2  = (const float*)d_in[4];
    const float* b2  = (const float*)d_in[5];
    const float* W3  = (const float*)d_in[6];
    const float* b3  = (const float*)d_in[7];
    const float* g1  = (const float*)d_in[8];
    const float* bt1 = (const float*)d_in[9];
    const float* g2  = (const float*)d_in[10];
    const float* bt2 = (const float*)d_in[11];
    const float* Wf  = (const float*)d_in[12];
    const float* bf  = (const float*)d_in[13];
    float* out = (float*)d_out;

    const int nN = in_sizes[0] / 64;
    const int nE = in_sizes[1] / 2;
    const int* src = ei;
    const int* dst = ei + nE;

    size_t off = 0;
    auto carve = [&](size_t bytes) -> void* {
        void* p = (char*)d_ws + off;
        off += (bytes + 255) & ~(size_t)255;
        return p;
    };
    float*          dinv = (float*)carve((size_t)nN * 4);
    int*            cur  = (int*)carve((size_t)nN * 4);
    int*            csrc = (int*)carve((size_t)nN * DMAX * 4);
    unsigned short* slab = (unsigned short*)carve((size_t)nN * 64 * 2 * 5);  // [5][nN][64]; 48-slab aliases
    unsigned short* H    = (unsigned short*)carve((size_t)nN * NHID * 2);
    float*          bns  = (float*)carve(2 * NHID * 4);

    const size_t ts64 = (size_t)nN * 64;   // term stride (elements), layer 1
    const size_t ts48 = (size_t)nN * NHID; // term stride, layers 2/3 (aliased onto slab)

    hipMemsetAsync(dinv, 0, (size_t)nN * 4, stream);
    hipMemsetAsync(cur, 0, (size_t)nN * 4, stream);

    const int gE = (nE + 255) / 256;
    k_setup<<<gE, 256, 0, stream>>>(src, dst, dinv, cur, csrc, nE);
    k_dinv<<<(nN + 255) / 256, 256, 0, stream>>>(dinv, nN);
    k_cast<<<(nN * 16 + 255) / 256, 256, 0, stream>>>((const float4*)x, (uint2*)slab, nN * 16);

    const int gP = (nN + 3) / 4;
    const dim3 blkP(64, 4);
    const int gM = 512;

    auto prop = [&](const unsigned short* Tin, const unsigned short* Tprev,
                    unsigned short* Tout, int NVw, int mode) {
        if (NVw == 8)
            k_prop<8><<<gP, blkP, 0, stream>>>((const uint4*)Tin, (const uint4*)Tprev,
                                               (uint4*)Tout, cur, csrc, dinv, nN, mode);
        else
            k_prop<6><<<gP, blkP, 0, stream>>>((const uint4*)Tin, (const uint4*)Tprev,
                                               (uint4*)Tout, cur, csrc, dinv, nN, mode);
    };

    // ---- layer 1 (Win=64): terms in slab[0..4] with stride ts64 ----
    unsigned short* L1[5];
    for (int t = 0; t < 5; ++t) L1[t] = slab + t * ts64;
    prop(L1[0], nullptr, L1[1], 8, 0);
    prop(L1[1], L1[0], L1[2], 8, 1);
    prop(L1[2], L1[1], L1[3], 8, 1);
    prop(L1[3], L1[2], L1[4], 8, 1);
    hipMemsetAsync(bns, 0, 2 * NHID * 4, stream);
    k_mmf<64, 0><<<gM, 256, 0, stream>>>(slab, W1, b1, H, bns, nullptr, nullptr, nullptr, nN);
    k_bn_apply<<<(nN + 7) / 8, dim3(NHID, 8), 0, stream>>>(H, slab, bns, g1, bt1, nN);  // -> 48-term0

    // ---- layer 2 (Win=48): terms in slab[0..4] with stride ts48 (aliased) ----
    unsigned short* L2[5];
    for (int t = 0; t < 5; ++t) L2[t] = slab + t * ts48;
    prop(L2[0], nullptr, L2[1], 6, 0);
    prop(L2[1], L2[0], L2[2], 6, 1);
    prop(L2[2], L2[1], L2[3], 6, 1);
    prop(L2[3], L2[2], L2[4], 6, 1);
    hipMemsetAsync(bns, 0, 2 * NHID * 4, stream);
    k_mmf<48, 0><<<gM, 256, 0, stream>>>(slab, W2, b2, H, bns, nullptr, nullptr, nullptr, nN);
    k_bn_apply<<<(nN + 7) / 8, dim3(NHID, 8), 0, stream>>>(H, slab, bns, g2, bt2, nN);

    // ---- layer 3 (Win=48) + fused final linear ----
    prop(L2[0], nullptr, L2[1], 6, 0);
    prop(L2[1], L2[0], L2[2], 6, 1);
    prop(L2[2], L2[1], L2[3], 6, 1);
    prop(L2[3], L2[2], L2[4], 6, 1);
    k_mmf<48, 1><<<gM, 256, 0, stream>>>(slab, W3, b3, nullptr, nullptr, Wf, bf, out, nN);
}

// Round 7
// 813.871 us; speedup vs baseline: 1.8359x; 1.0441x over previous
//
#include <hip/hip_runtime.h>

#define NHID 48
#define BN_EPS 1e-5f
#define SLOPE 0.01f
#define DMAX 64

typedef short short8 __attribute__((ext_vector_type(8)));
typedef float f32x4 __attribute__((ext_vector_type(4)));

// ---------- bf16 helpers (fp32 compute, bf16 storage, RNE pack) ----------
__device__ __forceinline__ float bf_lo(unsigned u) { union { unsigned i; float f; } c; c.i = u << 16; return c.f; }
__device__ __forceinline__ float bf_hi(unsigned u) { union { unsigned i; float f; } c; c.i = u & 0xffff0000u; return c.f; }
__device__ __forceinline__ unsigned bf_rne(float x) { union { float f; unsigned i; } c; c.f = x; return (c.i + 0x7fffu + ((c.i >> 16) & 1u)) >> 16; }
__device__ __forceinline__ unsigned packbf(float lo, float hi) { return bf_rne(lo) | (bf_rne(hi) << 16); }

__device__ __forceinline__ void acc8(float (&a)[8], float w, const uint4& v) {
    a[0] = fmaf(w, bf_lo(v.x), a[0]); a[1] = fmaf(w, bf_hi(v.x), a[1]);
    a[2] = fmaf(w, bf_lo(v.y), a[2]); a[3] = fmaf(w, bf_hi(v.y), a[3]);
    a[4] = fmaf(w, bf_lo(v.z), a[4]); a[5] = fmaf(w, bf_hi(v.z), a[5]);
    a[6] = fmaf(w, bf_lo(v.w), a[6]); a[7] = fmaf(w, bf_hi(v.w), a[7]);
}

// ---------- setup: out-degree histogram + padded-CSR scatter (grid-stride) ----------
__global__ void k_setup(const int* __restrict__ src, const int* __restrict__ dst,
                        float* __restrict__ degf, int* __restrict__ cur,
                        int* __restrict__ csrc, int nE) {
    for (int e = blockIdx.x * blockDim.x + threadIdx.x; e < nE; e += gridDim.x * blockDim.x) {
        int s = src[e], d = dst[e];
        atomicAdd(&degf[s], 1.0f);
        int r = atomicAdd(&cur[d], 1);
        if (r < DMAX) csrc[(size_t)d * DMAX + r] = s;
    }
}

__global__ void k_dinv(float* __restrict__ deg, int nN) {
    for (int i = blockIdx.x * blockDim.x + threadIdx.x; i < nN; i += gridDim.x * blockDim.x) {
        float d = deg[i];
        deg[i] = (d > 0.f) ? rsqrtf(d) : 0.f;
    }
}

__global__ void k_cast(const float4* __restrict__ in, uint2* __restrict__ outv, int n4) {
    for (int i = blockIdx.x * blockDim.x + threadIdx.x; i < n4; i += gridDim.x * blockDim.x) {
        float4 v = in[i];
        outv[i] = make_uint2(packbf(v.x, v.y), packbf(v.z, v.w));
    }
}

// ---------- propagation: one wave per node, grid-stride (resident waves) ----------
// lane = y*8 + x : y = edge slot (0..7), x = uint4 feature chunk (0..NV-1)
template <int NV>
__global__ void k_prop(const uint4* __restrict__ Tin, const uint4* __restrict__ Tprev,
                       uint4* __restrict__ Tout, const int* __restrict__ cnt,
                       const int* __restrict__ csrc, const float* __restrict__ dinv,
                       int nN, int mode) {
    const int lane = threadIdx.x;
    const int x = lane & 7;
    const int y = lane >> 3;
    for (int n = blockIdx.x * 4 + threadIdx.y; n < nN; n += gridDim.x * 4) {
        int eb = n << 6;
        int c = cnt[n]; if (c > DMAX) c = DMAX;
        float a[8] = {0.f, 0.f, 0.f, 0.f, 0.f, 0.f, 0.f, 0.f};
        for (int it = 0; it < c; it += 16) {
            int j0 = it + y, j1 = it + 8 + y;
            int s0 = (j0 < c) ? csrc[eb + j0] : 0;
            int s1 = (j1 < c) ? csrc[eb + j1] : 0;
            float w0 = (j0 < c) ? dinv[s0] : 0.f;
            float w1 = (j1 < c) ? dinv[s1] : 0.f;
            if (x < NV) {
                uint4 q0 = Tin[(size_t)s0 * NV + x];
                uint4 q1 = Tin[(size_t)s1 * NV + x];
                acc8(a, w0, q0);
                acc8(a, w1, q1);
            }
        }
#pragma unroll
        for (int k = 0; k < 8; ++k) {
            float v = a[k];
            v += __shfl_xor(v, 8);
            v += __shfl_xor(v, 16);
            v += __shfl_xor(v, 32);
            a[k] = v;
        }
        if (y == 0 && x < NV) {
            float dn = -dinv[n];
            size_t o = (size_t)n * NV + x;
            uint4 r;
            if (mode) {
                uint4 p = Tprev[o];
                float t = 2.f * dn;
                r.x = packbf(fmaf(t, a[0], -bf_lo(p.x)), fmaf(t, a[1], -bf_hi(p.x)));
                r.y = packbf(fmaf(t, a[2], -bf_lo(p.y)), fmaf(t, a[3], -bf_hi(p.y)));
                r.z = packbf(fmaf(t, a[4], -bf_lo(p.z)), fmaf(t, a[5], -bf_hi(p.z)));
                r.w = packbf(fmaf(t, a[6], -bf_lo(p.w)), fmaf(t, a[7], -bf_hi(p.w)));
            } else {
                r.x = packbf(dn * a[0], dn * a[1]);
                r.y = packbf(dn * a[2], dn * a[3]);
                r.z = packbf(dn * a[4], dn * a[5]);
                r.w = packbf(dn * a[6], dn * a[7]);
            }
            Tout[o] = r;
        }
    }
}

// ---------- MFMA matmul over 5 Chebyshev terms ----------
// Tslab: [5][nN][WIN] bf16 contiguous; W: [K=5*WIN][48] fp32 (k = t*WIN+f matches)
// MODE 0: Hout(bf16) = bias + slab@W; BN sums epilogue -> bns
// MODE 1: out(f32)   = (bias + slab@W) @ Wf + bf
template <int WIN, int MODE>
__global__ __launch_bounds__(256) void k_mmf(
    const unsigned short* __restrict__ Tslab, const float* __restrict__ Wb,
    const float* __restrict__ bias, unsigned short* __restrict__ Hout,
    float* __restrict__ bns, const float* __restrict__ Wf,
    const float* __restrict__ bfin, float* __restrict__ out, int nN) {
    constexpr int K = 5 * WIN;
    constexpr int NC = (K + 31) / 32;
    const int lane = threadIdx.x & 63;
    const int wid = threadIdx.x >> 6;
    const int col = lane & 15;
    const int sub = lane >> 4;
    const size_t termStride = (size_t)nN * WIN;

    short8 bfrag[3][NC];
#pragma unroll
    for (int ct = 0; ct < 3; ++ct) {
        int j = ct * 16 + col;
#pragma unroll
        for (int c = 0; c < NC; ++c) {
            short8 b;
#pragma unroll
            for (int r = 0; r < 8; ++r) {
                int k = c * 32 + sub * 8 + r;
                float w = (k < K) ? Wb[(size_t)k * 48 + j] : 0.f;
                b[r] = (short)bf_rne(w);
            }
            bfrag[ct][c] = b;
        }
    }
    float bj0 = bias[col], bj1 = bias[16 + col], bj2 = bias[32 + col];
    float wf00 = 0.f, wf01 = 0.f, wf02 = 0.f, wf10 = 0.f, wf11 = 0.f, wf12 = 0.f;
    float bf0 = 0.f, bf1 = 0.f;
    if (MODE == 1) {
        wf00 = Wf[(col) * 2 + 0];      wf10 = Wf[(col) * 2 + 1];
        wf01 = Wf[(16 + col) * 2 + 0]; wf11 = Wf[(16 + col) * 2 + 1];
        wf02 = Wf[(32 + col) * 2 + 0]; wf12 = Wf[(32 + col) * 2 + 1];
        bf0 = bfin[0]; bf1 = bfin[1];
    }
    float s0 = 0.f, s1 = 0.f, s2 = 0.f, q0 = 0.f, q1 = 0.f, q2 = 0.f;

    const int ntiles = (nN + 15) >> 4;
    for (int tile = blockIdx.x * 4 + wid; tile < ntiles; tile += gridDim.x * 4) {
        int n0 = tile << 4;
        int arow = n0 + col;
        bool rowok = arow < nN;
        f32x4 acc0 = {0.f, 0.f, 0.f, 0.f};
        f32x4 acc1 = {0.f, 0.f, 0.f, 0.f};
        f32x4 acc2 = {0.f, 0.f, 0.f, 0.f};
#pragma unroll
        for (int c = 0; c < NC; ++c) {
            int k = c * 32 + sub * 8;
            short8 a = {};
            if (rowok && k < K) {
                int t = k / WIN, f = k % WIN;
                a = *(const short8*)(Tslab + (size_t)t * termStride + (size_t)arow * WIN + f);
            }
            acc0 = __builtin_amdgcn_mfma_f32_16x16x32_bf16(a, bfrag[0][c], acc0, 0, 0, 0);
            acc1 = __builtin_amdgcn_mfma_f32_16x16x32_bf16(a, bfrag[1][c], acc1, 0, 0, 0);
            acc2 = __builtin_amdgcn_mfma_f32_16x16x32_bf16(a, bfrag[2][c], acc2, 0, 0, 0);
        }
        int nb = n0 + sub * 4;
        if (MODE == 0) {
#pragma unroll
            for (int r = 0; r < 4; ++r) {
                int n = nb + r;
                if (n < nN) {
                    float v0 = acc0[r] + bj0;
                    float v1 = acc1[r] + bj1;
                    float v2 = acc2[r] + bj2;
                    size_t ro = (size_t)n * NHID;
                    Hout[ro + col]      = (unsigned short)bf_rne(v0);
                    Hout[ro + 16 + col] = (unsigned short)bf_rne(v1);
                    Hout[ro + 32 + col] = (unsigned short)bf_rne(v2);
                    s0 += v0; q0 += v0 * v0;
                    s1 += v1; q1 += v1 * v1;
                    s2 += v2; q2 += v2 * v2;
                }
            }
        } else {
#pragma unroll
            for (int r = 0; r < 4; ++r) {
                float p0 = fmaf(acc0[r] + bj0, wf00, fmaf(acc1[r] + bj1, wf01, (acc2[r] + bj2) * wf02));
                float p1 = fmaf(acc0[r] + bj0, wf10, fmaf(acc1[r] + bj1, wf11, (acc2[r] + bj2) * wf12));
                p0 += __shfl_xor(p0, 1); p0 += __shfl_xor(p0, 2);
                p0 += __shfl_xor(p0, 4); p0 += __shfl_xor(p0, 8);
                p1 += __shfl_xor(p1, 1); p1 += __shfl_xor(p1, 2);
                p1 += __shfl_xor(p1, 4); p1 += __shfl_xor(p1, 8);
                int n = nb + r;
                if (col == 0 && n < nN) {
                    out[(size_t)n * 2 + 0] = p0 + bf0;
                    out[(size_t)n * 2 + 1] = p1 + bf1;
                }
            }
        }
    }
    if (MODE == 0) {
        s0 += __shfl_xor(s0, 16); s0 += __shfl_xor(s0, 32);
        s1 += __shfl_xor(s1, 16); s1 += __shfl_xor(s1, 32);
        s2 += __shfl_xor(s2, 16); s2 += __shfl_xor(s2, 32);
        q0 += __shfl_xor(q0, 16); q0 += __shfl_xor(q0, 32);
        q1 += __shfl_xor(q1, 16); q1 += __shfl_xor(q1, 32);
        q2 += __shfl_xor(q2, 16); q2 += __shfl_xor(q2, 32);
        __shared__ float red[4][96];
        if (lane < 16) {
            red[wid][col]      = s0; red[wid][16 + col] = s1; red[wid][32 + col] = s2;
            red[wid][48 + col] = q0; red[wid][64 + col] = q1; red[wid][80 + col] = q2;
        }
        __syncthreads();
        int t = threadIdx.x;
        if (t < 96) atomicAdd(&bns[t], red[0][t] + red[1][t] + red[2][t] + red[3][t]);
    }
}

// ---------- batchnorm apply + LeakyReLU (grid-stride) ----------
__global__ void k_bn_apply(const unsigned short* __restrict__ Hin, unsigned short* __restrict__ T0,
                           const float* __restrict__ sums, const float* __restrict__ g,
                           const float* __restrict__ b, int nN) {
    int col = threadIdx.x;
    float inv = 1.f / (float)nN;
    float mu = sums[col] * inv;
    float var = sums[NHID + col] * inv - mu * mu;
    float rs = rsqrtf(var + BN_EPS) * g[col];
    float bb = b[col];
    for (int n = blockIdx.x * 8 + threadIdx.y; n < nN; n += gridDim.x * 8) {
        size_t o = (size_t)n * NHID + col;
        float y = (bf_lo(Hin[o]) - mu) * rs + bb;
        y = (y >= 0.f) ? y : SLOPE * y;
        T0[o] = (unsigned short)bf_rne(y);
    }
}

extern "C" void kernel_launch(void* const* d_in, const int* in_sizes, int n_in,
                              void* d_out, int out_size, void* d_ws, size_t ws_size,
                              hipStream_t stream) {
    const float* x   = (const float*)d_in[0];
    const int*   ei  = (const int*)d_in[1];
    const float* W1  = (const float*)d_in[2];
    const float* b1  = (const float*)d_in[3];
    const float* W2  = (const float*)d_in[4];
    const float* b2  = (const float*)d_in[5];
    const float* W3  = (const float*)d_in[6];
    const float* b3  = (const float*)d_in[7];
    const float* g1  = (const float*)d_in[8];
    const float* bt1 = (const float*)d_in[9];
    const float* g2  = (const float*)d_in[10];
    const float* bt2 = (const float*)d_in[11];
    const float* Wf  = (const float*)d_in[12];
    const float* bf  = (const float*)d_in[13];
    float* out = (float*)d_out;

    const int nN = in_sizes[0] / 64;
    const int nE = in_sizes[1] / 2;
    const int* src = ei;
    const int* dst = ei + nE;

    size_t off = 0;
    auto carve = [&](size_t bytes) -> void* {
        void* p = (char*)d_ws + off;
        off += (bytes + 255) & ~(size_t)255;
        return p;
    };
    float*          dinv = (float*)carve((size_t)nN * 4);
    int*            cur  = (int*)carve((size_t)nN * 4);
    int*            csrc = (int*)carve((size_t)nN * DMAX * 4);
    unsigned short* slab = (unsigned short*)carve((size_t)nN * 64 * 2 * 5);  // [5][nN][64]; 48-slab aliases
    unsigned short* H    = (unsigned short*)carve((size_t)nN * NHID * 2);
    float*          bns  = (float*)carve(2 * NHID * 4);

    const size_t ts64 = (size_t)nN * 64;
    const size_t ts48 = (size_t)nN * NHID;

    hipMemsetAsync(dinv, 0, (size_t)nN * 4, stream);
    hipMemsetAsync(cur, 0, (size_t)nN * 4, stream);

    k_setup<<<4096, 256, 0, stream>>>(src, dst, dinv, cur, csrc, nE);
    k_dinv<<<1024, 256, 0, stream>>>(dinv, nN);
    k_cast<<<2048, 256, 0, stream>>>((const float4*)x, (uint2*)slab, nN * 16);

    const int gP = 2048;             // resident grid: 8192 waves = 32/CU, grid-stride
    const dim3 blkP(64, 4);
    const int gM = 512;

    auto prop = [&](const unsigned short* Tin, const unsigned short* Tprev,
                    unsigned short* Tout, int NVw, int mode) {
        if (NVw == 8)
            k_prop<8><<<gP, blkP, 0, stream>>>((const uint4*)Tin, (const uint4*)Tprev,
                                               (uint4*)Tout, cur, csrc, dinv, nN, mode);
        else
            k_prop<6><<<gP, blkP, 0, stream>>>((const uint4*)Tin, (const uint4*)Tprev,
                                               (uint4*)Tout, cur, csrc, dinv, nN, mode);
    };

    // ---- layer 1 (Win=64) ----
    unsigned short* L1[5];
    for (int t = 0; t < 5; ++t) L1[t] = slab + t * ts64;
    prop(L1[0], nullptr, L1[1], 8, 0);
    prop(L1[1], L1[0], L1[2], 8, 1);
    prop(L1[2], L1[1], L1[3], 8, 1);
    prop(L1[3], L1[2], L1[4], 8, 1);
    hipMemsetAsync(bns, 0, 2 * NHID * 4, stream);
    k_mmf<64, 0><<<gM, 256, 0, stream>>>(slab, W1, b1, H, bns, nullptr, nullptr, nullptr, nN);
    k_bn_apply<<<1024, dim3(NHID, 8), 0, stream>>>(H, slab, bns, g1, bt1, nN);

    // ---- layer 2 (Win=48) ----
    unsigned short* L2[5];
    for (int t = 0; t < 5; ++t) L2[t] = slab + t * ts48;
    prop(L2[0], nullptr, L2[1], 6, 0);
    prop(L2[1], L2[0], L2[2], 6, 1);
    prop(L2[2], L2[1], L2[3], 6, 1);
    prop(L2[3], L2[2], L2[4], 6, 1);
    hipMemsetAsync(bns, 0, 2 * NHID * 4, stream);
    k_mmf<48, 0><<<gM, 256, 0, stream>>>(slab, W2, b2, H, bns, nullptr, nullptr, nullptr, nN);
    k_bn_apply<<<1024, dim3(NHID, 8), 0, stream>>>(H, slab, bns, g2, bt2, nN);

    // ---- layer 3 (Win=48) + fused final linear ----
    prop(L2[0], nullptr, L2[1], 6, 0);
    prop(L2[1], L2[0], L2[2], 6, 1);
    prop(L2[2], L2[1], L2[3], 6, 1);
    prop(L2[3], L2[2], L2[4], 6, 1);
    k_mmf<48, 1><<<gM, 256, 0, stream>>>(slab, W3, b3, nullptr, nullptr, Wf, bf, out, nN);
}